// Round 10
// baseline (496.398 us; speedup 1.0000x reference)
//
#include <hip/hip_runtime.h>
#include <math.h>

// Problem constants
#define NSEQ 4
#define BATCH 256
#define T 64
#define FIN 32
#define S 512
#define KTOT 544     // FIN + S unified k-dimension

// Pipelined decomposition: 4 lanes concurrent (lane i lags i-1 by 1 step).
// Per lane: 16 groups x 16 rows, 8 slice-WGs x 64 cols. 4*16*8 = 512 WGs.
// NT=256 (4 waves), 2 WG/CU. Wave -> 16x16 MFMA tile, 17 K-tiles of
// mfma_f32_16x16x32_bf16, split-bf16 (hi+lo, 3 products) for accuracy.
#define NT 256
#define NWG 512
#define RPG 16
#define SW 64
#define DEPTH 4
#define NKT 17       // K-tiles of 32 (544/32)

// ws float offsets
#define RING_SZ  (4ull * DEPTH * BATCH * S)        // 8 MB state ring
#define OUTP_OFF RING_SZ                            // [gid][sl][16] partials
#define CTL_OFF  (RING_SZ + 16384ull)               // counters: gid*32 uints

#define FLAG_MAGIC 0x13572468u

#define AS 552   // A-LDS row stride in bf16 elems (544+8; 16B-aligned rows,
                 // and 276 dw ≡ 20 mod 32 -> 2 rows/wave hit disjoint banks
                 // with the 1-dword-stride b32 staging writes below)

typedef __attribute__((ext_vector_type(8))) short short8;  // 8 bf16 (4 VGPRs)
typedef __attribute__((ext_vector_type(4))) float f32x4;   // MFMA C/D

// ---- split-bf16 helpers ----------------------------------------------------
__device__ __forceinline__ unsigned short bf_hi(float f) {
  return (unsigned short)(__float_as_uint(f) >> 16);
}
__device__ __forceinline__ float bf_hi_f(float f) {
  return __uint_as_float(__float_as_uint(f) & 0xFFFF0000u);
}

__device__ __forceinline__ unsigned ld_cnt(const unsigned* p) {
  return __hip_atomic_load(p, __ATOMIC_RELAXED, __HIP_MEMORY_SCOPE_AGENT);
}

// ---- coherent (MALL) ring I/O via sc0 sc1 asm ------------------------------
__device__ __forceinline__ void cstore1(float* p, float v) {
  asm volatile("global_store_dword %0, %1, off sc0 sc1" :: "v"(p), "v"(v) : "memory");
}
__device__ __forceinline__ float cload1(const float* p) {
  float v;
  asm volatile("global_load_dword %0, %1, off sc0 sc1\n\ts_waitcnt vmcnt(0)"
               : "=v"(v) : "v"(p) : "memory");
  return v;
}
// 8B/lane ring loads: lane gch owns elems {2gch, 2gch+1} of a row; 8 j-blocks
// of 64 floats. Wave = 2 rows x 32 lanes x 8B contiguous -> packed sectors.
__device__ __forceinline__ void cload8_f2(float2* d, const float* p) {
  asm volatile(
      "global_load_dwordx2 %0, %8, off sc0 sc1\n\t"
      "global_load_dwordx2 %1, %8, off offset:256 sc0 sc1\n\t"
      "global_load_dwordx2 %2, %8, off offset:512 sc0 sc1\n\t"
      "global_load_dwordx2 %3, %8, off offset:768 sc0 sc1\n\t"
      "global_load_dwordx2 %4, %8, off offset:1024 sc0 sc1\n\t"
      "global_load_dwordx2 %5, %8, off offset:1280 sc0 sc1\n\t"
      "global_load_dwordx2 %6, %8, off offset:1536 sc0 sc1\n\t"
      "global_load_dwordx2 %7, %8, off offset:1792 sc0 sc1\n\t"
      "s_waitcnt vmcnt(0)"
      : "=&v"(d[0]), "=&v"(d[1]), "=&v"(d[2]), "=&v"(d[3]),
        "=&v"(d[4]), "=&v"(d[5]), "=&v"(d[6]), "=&v"(d[7])
      : "v"(p) : "memory");
}
__device__ __forceinline__ void cload16_f2(float2* h, float2* q,
                                           const float* ph, const float* pp) {
  asm volatile(
      "global_load_dwordx2 %0, %16, off sc0 sc1\n\t"
      "global_load_dwordx2 %1, %16, off offset:256 sc0 sc1\n\t"
      "global_load_dwordx2 %2, %16, off offset:512 sc0 sc1\n\t"
      "global_load_dwordx2 %3, %16, off offset:768 sc0 sc1\n\t"
      "global_load_dwordx2 %4, %16, off offset:1024 sc0 sc1\n\t"
      "global_load_dwordx2 %5, %16, off offset:1280 sc0 sc1\n\t"
      "global_load_dwordx2 %6, %16, off offset:1536 sc0 sc1\n\t"
      "global_load_dwordx2 %7, %16, off offset:1792 sc0 sc1\n\t"
      "global_load_dwordx2 %8, %17, off sc0 sc1\n\t"
      "global_load_dwordx2 %9, %17, off offset:256 sc0 sc1\n\t"
      "global_load_dwordx2 %10, %17, off offset:512 sc0 sc1\n\t"
      "global_load_dwordx2 %11, %17, off offset:768 sc0 sc1\n\t"
      "global_load_dwordx2 %12, %17, off offset:1024 sc0 sc1\n\t"
      "global_load_dwordx2 %13, %17, off offset:1280 sc0 sc1\n\t"
      "global_load_dwordx2 %14, %17, off offset:1536 sc0 sc1\n\t"
      "global_load_dwordx2 %15, %17, off offset:1792 sc0 sc1\n\t"
      "s_waitcnt vmcnt(0)"
      : "=&v"(h[0]), "=&v"(h[1]), "=&v"(h[2]), "=&v"(h[3]),
        "=&v"(h[4]), "=&v"(h[5]), "=&v"(h[6]), "=&v"(h[7]),
        "=&v"(q[0]), "=&v"(q[1]), "=&v"(q[2]), "=&v"(q[3]),
        "=&v"(q[4]), "=&v"(q[5]), "=&v"(q[6]), "=&v"(q[7])
      : "v"(ph), "v"(pp) : "memory");
}
// batched 3-counter read: one RTT instead of 3 serial polls
__device__ __forceinline__ void cload3_u(unsigned& a, unsigned& b, unsigned& c,
                                         const unsigned* pa, const unsigned* pb,
                                         const unsigned* pc) {
  asm volatile(
      "global_load_dword %0, %3, off sc0 sc1\n\t"
      "global_load_dword %1, %4, off sc0 sc1\n\t"
      "global_load_dword %2, %5, off sc0 sc1\n\t"
      "s_waitcnt vmcnt(0)"
      : "=&v"(a), "=&v"(b), "=&v"(c)
      : "v"(pa), "v"(pb), "v"(pc) : "memory");
}

extern "C" __global__ void __launch_bounds__(NT, 1)
rnn_mfma2(const float* __restrict__ x,      // [4][256][64][32]
          const float* __restrict__ Wcell,  // [4][544][512]
          const float* __restrict__ bcell,  // [4][512]
          const float* __restrict__ Wcomb,  // [3][1024]
          const float* __restrict__ bcomb,  // [3]
          const float* __restrict__ Wout,   // [512]
          float* __restrict__ out,          // [1024] = [lane][batch]
          float* __restrict__ ws)
{
  const int b = blockIdx.x;
  // XCD-clustered swizzle (perf heuristic only): all 32 WGs of a grp-chain
  // (4 lanes x 8 slices) share b%8 -> likely same XCD -> tighter barrier skew.
  const int xcd  = b & 7;
  const int sl   = (b >> 3) & 7;
  const int gid  = ((b >> 6) << 3) + xcd;  // 0..63 = lane*16 + grp
  const int lane = gid >> 4;
  const int grp  = gid & 15;
  const int r0 = grp * RPG, sb = sl * SW;
  const int tid = threadIdx.x;

  __shared__ __align__(16) unsigned short A1[RPG * AS];  // 17.3 KB hi [x|hc]
  __shared__ __align__(16) unsigned short A2[RPG * AS];  // 17.3 KB lo
  __shared__ float wg_lds[2 * S];                        //  4.0 KB gate weights
  __shared__ float obuf[64];
  __shared__ float fbuf[128];

  float* ring = ws;
  unsigned* ctl      = (unsigned*)(ws + CTL_OFF);
  unsigned* cnt_own  = ctl + gid * 32;
  unsigned* flg_own  = cnt_own + 16;
  unsigned* cnt_prod = ctl + (gid - 16) * 32;  // valid iff lane>0
  unsigned* cnt_cons = ctl + (gid + 16) * 32;  // valid iff lane<3
  const unsigned* pp_prod = (lane > 0) ? cnt_prod : cnt_own;  // safe dummies
  const unsigned* pp_cons = (lane < 3) ? cnt_cons : cnt_own;

  // ---- init handshake (poison-keyed flag) ----
  if (sl == 0 && tid == 0) {
    __hip_atomic_store(cnt_own, 0u, __ATOMIC_RELAXED, __HIP_MEMORY_SCOPE_AGENT);
    __hip_atomic_store(flg_own, FLAG_MAGIC, __ATOMIC_RELEASE, __HIP_MEMORY_SCOPE_AGENT);
  }
  if (tid == 0) {
    while (__hip_atomic_load(flg_own, __ATOMIC_ACQUIRE, __HIP_MEMORY_SCOPE_AGENT) != FLAG_MAGIC)
      __builtin_amdgcn_s_sleep(1);
    if (lane > 0)
      while (__hip_atomic_load(cnt_prod + 16, __ATOMIC_ACQUIRE, __HIP_MEMORY_SCOPE_AGENT) != FLAG_MAGIC)
        __builtin_amdgcn_s_sleep(1);
    if (lane < 3)
      while (__hip_atomic_load(cnt_cons + 16, __ATOMIC_ACQUIRE, __HIP_MEMORY_SCOPE_AGENT) != FLAG_MAGIC)
        __builtin_amdgcn_s_sleep(1);
  }

  // ---- per-thread constants ----
  const float* Wc = Wcell + (size_t)lane * KTOT * S;
  const int wl = tid & 63, wt = tid >> 6;
  const int bn = wl & 15, q = wl >> 4;
  const int ncol = sb + wt * 16 + bn;

  // B-frags via coalesced LDS transpose (R9's 2KB-stride column reads were
  // ~570 MB of scattered HBM fetch; this is 64B-sector coalesced, L2-reused).
  short8 B1[NKT], B2[NKT];
  {
    float* wlds = (float*)A1;           // 8.7 KB scratch before first A1 use
    const int lr = tid >> 3;            // 0..31: k-row within tile
    const int lc = (tid & 7) * 8;       // col-of-8 within 64-col slice
    #pragma unroll
    for (int kt = 0; kt < NKT; ++kt) {
      const float* src = Wc + (size_t)(kt * 32 + lr) * S + sb + lc;
      const float4 w0 = *(const float4*)src;
      const float4 w1 = *(const float4*)(src + 4);
      __syncthreads();                  // scratch free (prev kt consumed)
      *(float4*)&wlds[lr * 68 + lc]     = w0;
      *(float4*)&wlds[lr * 68 + lc + 4] = w1;
      __syncthreads();
      short8 b1, b2;
      #pragma unroll
      for (int j = 0; j < 8; ++j) {
        const float w = wlds[(q * 8 + j) * 68 + wt * 16 + bn];
        b1[j] = (short)bf_hi(w);
        b2[j] = (short)bf_hi(w - bf_hi_f(w));
      }
      B1[kt] = b1; B2[kt] = b2;
    }
  }
  const float bcv = bcell[lane * S + ncol];
  const float wov = Wout[ncol];
  for (int idx = tid; idx < 2 * S; idx += NT)
    wg_lds[idx] = (lane > 0) ? Wcomb[(size_t)(lane - 1) * 2 * S + idx] : 0.0f;
  const float bg = (lane > 0) ? bcomb[lane - 1] : 0.0f;
  // stage/gate mapping: 32 threads per row (elems {2gch,2gch+1} + j*64)
  const int grow = tid >> 5, gch = tid & 31;
  __syncthreads();

  float oacc[4] = {0.f, 0.f, 0.f, 0.f};

  for (int t = 0; t < T; ++t) {
    // ---- phase A: x stage + batched poll (1 RTT fast path) ----
    {
      const float f0 = x[(((size_t)lane * BATCH + r0 + grow) * T + t) * FIN + gch];
      const float f1 = x[(((size_t)lane * BATCH + r0 + grow + 8) * T + t) * FIN + gch];
      A1[grow * AS + gch]       = bf_hi(f0);
      A2[grow * AS + gch]       = bf_hi(f0 - bf_hi_f(f0));
      A1[(grow + 8) * AS + gch] = bf_hi(f1);
      A2[(grow + 8) * AS + gch] = bf_hi(f1 - bf_hi_f(f1));
    }
    if (tid == 0) {
      unsigned co, cp, cc;
      cload3_u(co, cp, cc, cnt_own, pp_prod, pp_cons);
      if (t > 0 && co < 8u * (unsigned)t)
        while (ld_cnt(cnt_own) < 8u * (unsigned)t) {}
      if (lane > 0 && cp < 8u * (unsigned)(t + 1))
        while (ld_cnt(cnt_prod) < 8u * (unsigned)(t + 1)) {}
      if (lane < 3 && t >= DEPTH && cc < 8u * (unsigned)(t - 3))
        while (ld_cnt(cnt_cons) < 8u * (unsigned)(t - 3)) {}
    }
    __syncthreads();

    // ---- phase B: ring loads + wave-local gate (fp32) + split-stage hc ----
    #pragma unroll
    for (int pass = 0; pass < 2; ++pass) {
      const int row = pass * 8 + grow;
      float2 hv[8], pv[8];
      const float* hb = ring + ((size_t)(lane * DEPTH + ((t - 1) & 3)) * BATCH + r0 + row) * S + gch * 2;
      const float* pb = ring + ((size_t)((lane - 1) * DEPTH + (t & 3)) * BATCH + r0 + row) * S + gch * 2;
      if (t > 0) {
        if (lane > 0) cload16_f2(hv, pv, hb, pb);
        else          cload8_f2(hv, hb);
      } else {
        #pragma unroll
        for (int j = 0; j < 8; ++j) hv[j] = make_float2(0.f, 0.f);
        if (lane > 0) cload8_f2(pv, pb);
      }
      if (lane > 0) {
        float gs = 0.0f;
        #pragma unroll
        for (int j = 0; j < 8; ++j) {
          const float* wh = &wg_lds[j * 64 + gch * 2];
          const float* wp = wh + S;
          gs += hv[j].x * wh[0] + hv[j].y * wh[1];
          gs += pv[j].x * wp[0] + pv[j].y * wp[1];
        }
        gs += __shfl_xor(gs, 1);  gs += __shfl_xor(gs, 2);  gs += __shfl_xor(gs, 4);
        gs += __shfl_xor(gs, 8);  gs += __shfl_xor(gs, 16);  // 32-lane row halves
        const float w = 1.0f / (1.0f + __expf(-(gs + bg)));
        #pragma unroll
        for (int j = 0; j < 8; ++j) {  // hc = p + w*(h-p)
          hv[j].x = fmaf(w, hv[j].x - pv[j].x, pv[j].x);
          hv[j].y = fmaf(w, hv[j].y - pv[j].y, pv[j].y);
        }
      }
      // conflict-free staging: b32 writes, 1-dword lane stride (banks 0..31),
      // 2 rows/wave offset 276 dw ≡ 20 mod 32 -> exact 2-way (free)
      #pragma unroll
      for (int j = 0; j < 8; ++j) {
        const float2 v = hv[j];
        const unsigned hi2 = (unsigned)bf_hi(v.x) | ((unsigned)bf_hi(v.y) << 16);
        const unsigned lo2 = (unsigned)bf_hi(v.x - bf_hi_f(v.x))
                           | ((unsigned)bf_hi(v.y - bf_hi_f(v.y)) << 16);
        const int ai = row * AS + 32 + j * 64 + gch * 2;  // even -> 4B aligned
        *(unsigned*)&A1[ai] = hi2;
        *(unsigned*)&A2[ai] = lo2;
      }
    }
    __syncthreads();

    // ---- phase C: MFMA 16x16 tile, 17 K-tiles x 3 split products ----------
    f32x4 acc = {0.f, 0.f, 0.f, 0.f};
    {
      const unsigned short* ar1 = &A1[bn * AS + q * 8];
      const unsigned short* ar2 = &A2[bn * AS + q * 8];
      #pragma unroll
      for (int kt = 0; kt < NKT; ++kt) {
        const short8 a1 = *(const short8*)(ar1 + kt * 32);
        const short8 a2 = *(const short8*)(ar2 + kt * 32);
        acc = __builtin_amdgcn_mfma_f32_16x16x32_bf16(a1, B1[kt], acc, 0, 0, 0);
        acc = __builtin_amdgcn_mfma_f32_16x16x32_bf16(a1, B2[kt], acc, 0, 0, 0);
        acc = __builtin_amdgcn_mfma_f32_16x16x32_bf16(a2, B1[kt], acc, 0, 0, 0);
      }
    }

    // ---- epilogue: +bias, tanh, coherent ring store (D-layout direct) -----
    float* slot = ring + ((size_t)(lane * DEPTH + (t & 3)) * BATCH + r0) * S + sb;
    #pragma unroll
    for (int reg = 0; reg < 4; ++reg) {
      const float s2 = acc[reg] + bcv;
      const float aa = fabsf(s2), ee = __expf(2.0f * aa);
      const float tv = copysignf(1.0f - 2.0f / (ee + 1.0f), s2);
      cstore1(slot + (size_t)(q * 4 + reg) * S + wt * 16 + bn, tv);
      if (t == T - 1) oacc[reg] = tv * wov;
    }
    asm volatile("s_waitcnt vmcnt(0)" ::: "memory");  // own cstores at MALL
    __syncthreads();  // all threads drained -> safe to arrive + reuse A-LDS
    if (tid == 0)
      __hip_atomic_fetch_add(cnt_own, 1u, __ATOMIC_RELAXED, __HIP_MEMORY_SCOPE_AGENT);
  }

  // ---- output: out[lane*256 + r] = h_T[r] . Wout --------------------------
  #pragma unroll
  for (int reg = 0; reg < 4; ++reg) {
    float v = oacc[reg];
    v += __shfl_xor(v, 1); v += __shfl_xor(v, 2);
    v += __shfl_xor(v, 4); v += __shfl_xor(v, 8);  // sum 16 cols of the tile
    if (bn == 0) obuf[wt * 16 + q * 4 + reg] = v;
  }
  __syncthreads();
  if (tid < 16) {
    const float v = obuf[tid] + obuf[16 + tid] + obuf[32 + tid] + obuf[48 + tid];
    cstore1(ws + OUTP_OFF + (size_t)((gid * 8 + sl) * 16 + tid), v);
  }
  asm volatile("s_waitcnt vmcnt(0)" ::: "memory");
  __syncthreads();
  if (tid == 0)
    __hip_atomic_fetch_add(cnt_own, 1u, __ATOMIC_RELAXED, __HIP_MEMORY_SCOPE_AGENT);
  if (sl == 0) {
    if (tid == 0)
      while (ld_cnt(cnt_own) < 8u * (unsigned)(T + 1)) {}
    __syncthreads();
    if (tid < 128) {
      const int sli = tid >> 4, r = tid & 15;
      fbuf[tid] = cload1(ws + OUTP_OFF + (size_t)((gid * 8 + sli) * 16 + r));
    }
    __syncthreads();
    if (tid < 16) {
      float s2 = 0.f;
      #pragma unroll
      for (int sli = 0; sli < 8; ++sli) s2 += fbuf[sli * 16 + tid];
      out[lane * BATCH + r0 + tid] = s2;
    }
  }
}

extern "C" void kernel_launch(void* const* d_in, const int* in_sizes, int n_in,
                              void* d_out, int out_size, void* d_ws, size_t ws_size,
                              hipStream_t stream) {
  (void)in_sizes; (void)n_in; (void)out_size; (void)ws_size;
  rnn_mfma2<<<dim3(NWG), dim3(NT), 0, stream>>>(
      (const float*)d_in[0],   // inputs
      (const float*)d_in[1],   // W_cell
      (const float*)d_in[2],   // b_cell
      (const float*)d_in[3],   // W_comb
      (const float*)d_in[4],   // b_comb
      (const float*)d_in[5],   // W_out
      (float*)d_out,
      (float*)d_ws);
}